// Round 10
// baseline (159.188 us; speedup 1.0000x reference)
//
#include <hip/hip_runtime.h>

// GaussianSamplingPredict: B=1024, C=100, S=1000
//   L = cholesky(cov + 1e-6 I); t[b,s,d] = u[b,d] + sum_c z[s,c]*L[b,d,c]
//   out[b,d] = mean_s softmax_d(t[b,s,:])[d]
//
// R9: fix R8's regression. R8's trailing-update readlane used index kr>>1
// derived from w = tid>>6 - runtime wave-uniform but UNPROVABLY uniform to
// the compiler -> waterfall/spill lowering (WRITE_SIZE 29 -> 214 MB, +45 us).
// Fix: readfirstlane the index (stamps it uniform -> clean v_readlane with
// SGPR index). Panel readlanes (index jb+jj, provably uniform) untouched.
// Everything else identical to R8; absmax must stay bit-identical 9.77e-4.

#define CC    100
#define SS    1000
#define EPSF  1e-6f
#define NB    16     // Cholesky panel width
#define NDT   7      // d-tiles: 7*16 = 112 >= 100
#define NCS   4      // c-steps: 4*32 = 128 >= 102
#define NST   63     // s-tiles: 63*16 = 1008 >= 1000
#define LOG2E 1.44269504088896340736f

typedef short  s8 __attribute__((ext_vector_type(8)));   // 8 bf16 (4 VGPR)
typedef float  f4 __attribute__((ext_vector_type(4)));

__device__ inline unsigned short f2bf(float x) {          // round-nearest-even
    unsigned u = __float_as_uint(x);
    return (unsigned short)((u + 0x7fffu + ((u >> 16) & 1u)) >> 16);
}
__device__ inline float bf2f(unsigned short h) {
    return __uint_as_float(((unsigned)h) << 16);
}
__device__ inline float lane_bcast(float x, int lane) {   // provably-uniform idx
    return __int_as_float(__builtin_amdgcn_readlane(__float_as_int(x), lane));
}
__device__ inline float lane_bcast_u(float x, int lane) { // runtime-uniform idx
    const int sl = __builtin_amdgcn_readfirstlane(lane);  // stamp uniform
    return __int_as_float(__builtin_amdgcn_readlane(__float_as_int(x), sl));
}

// ---------------- K0: pack z -> bf16 frags (+ ones at c=100,101) ----------------
// frag layout: [stile][cstep][lane][j]; lane l: s = stile*16+(l&15),
// c = cstep*32 + (l>>4)*8 + j.
__global__ __launch_bounds__(256)
void zconv_kernel(const float* __restrict__ z, unsigned short* __restrict__ zb) {
    const int stile = blockIdx.x;            // 0..62
    const int cs = threadIdx.x >> 6;
    const int l  = threadIdx.x & 63;
    const int s  = stile * 16 + (l & 15);
    const int c0 = cs * 32 + (l >> 4) * 8;
    unsigned short v[8];
    #pragma unroll
    for (int j = 0; j < 8; ++j) {
        const int c = c0 + j;
        float x = 0.0f;
        if (c < CC)      x = (s < SS) ? z[(size_t)s * CC + c] : 0.0f;
        else if (c <= CC + 1) x = 1.0f;          // u_hi / u_lo slots
        v[j] = f2bf(x);
    }
    uint4 pk;
    pk.x = (unsigned)v[0] | ((unsigned)v[1] << 16);
    pk.y = (unsigned)v[2] | ((unsigned)v[3] << 16);
    pk.z = (unsigned)v[4] | ((unsigned)v[5] << 16);
    pk.w = (unsigned)v[6] | ((unsigned)v[7] << 16);
    reinterpret_cast<uint4*>(zb)[(stile * NCS + cs) * 64 + l] = pk;
}

// Register-resident panel factorization (wave 0 only).
// Lane l holds columns 2l, 2l+1 of each panel row (float2, b64 LDS traffic).
template<int NPAN>
__device__ inline void panel_factor(float* __restrict__ M, int jb, int l) {
    float2 P[NPAN];
    const int c0 = 2 * l;
    const bool vld = (c0 < CC);
    #pragma unroll
    for (int jj = 0; jj < NPAN; ++jj)
        P[jj] = vld ? *reinterpret_cast<const float2*>(&M[(jb + jj) * CC + c0])
                    : make_float2(0.f, 0.f);
    #pragma unroll
    for (int jj = 0; jj < NPAN; ++jj) {
        const int j = jb + jj;                 // provably uniform
        const float dsrc  = (j & 1) ? P[jj].y : P[jj].x;
        const float val   = lane_bcast(dsrc, j >> 1);
        const float dinv  = rsqrtf(val);
        const float s     = val * dinv;
        const float dinv2 = dinv * dinv;
        #pragma unroll
        for (int kk = jj + 1; kk < NPAN; ++kk) {
            const int k = jb + kk;
            const float tsrc = (k & 1) ? P[jj].y : P[jj].x;
            const float t = lane_bcast(tsrc, k >> 1) * dinv2;
            P[kk].x -= P[jj].x * t;
            P[kk].y -= P[jj].y * t;
        }
        P[jj].x = (c0 == j)     ? s : ((c0 > j)     ? P[jj].x * dinv : P[jj].x);
        P[jj].y = (c0 + 1 == j) ? s : ((c0 + 1 > j) ? P[jj].y * dinv : P[jj].y);
    }
    #pragma unroll
    for (int jj = 0; jj < NPAN; ++jj)
        if (vld) *reinterpret_cast<float2*>(&M[(jb + jj) * CC + c0]) = P[jj];
}

// ---------------- K1: blocked Cholesky (4 waves) + frag pack ----------------
// Storage: M[x*100+y] = L[y][x] for y>=x. Pack applies LOG2E scaling and
// appends u_hi/u_lo columns (c=100/101) and -1e30 pad sentinels.
__global__ __launch_bounds__(256, 4)
void chol_kernel(const float* __restrict__ cov, const float* __restrict__ u,
                 unsigned short* __restrict__ Lb) {
    __shared__ float M[CC * CC];
    const int tid = threadIdx.x;
    const int w   = tid >> 6;
    const int l   = tid & 63;
    const int b   = blockIdx.x;

    const float4* c4 = reinterpret_cast<const float4*>(cov + (size_t)b * CC * CC);
    for (int t = tid; t < CC * CC / 4; t += 256)
        reinterpret_cast<float4*>(M)[t] = c4[t];
    __syncthreads();
    for (int d = tid; d < CC; d += 256) M[d * CC + d] += EPSF;
    __syncthreads();

    for (int jb = 0; jb < CC; jb += NB) {
        const int jend = (jb + NB < CC) ? jb + NB : CC;

        // ---- panel factorization in wave-0 registers ----
        if (w == 0) {
            if (jend - jb == NB) panel_factor<NB>(M, jb, l);
            else                 panel_factor<CC - (CC / NB) * NB>(M, jb, l); // 4
        }
        __syncthreads();

        // ---- rank-16 trailing update, rows split across 4 waves ----
        // Lane l owns trailing columns i0 = jend+2l, i0+1 (float2).
        // bk (panel column k) broadcast from the P-cache of the owning lane
        // via v_readlane; index stamped uniform with readfirstlane (w-derived
        // indices are wave-uniform at runtime but divergent to the compiler).
        if (jend < CC) {
            const int i0 = jend + 2 * l;
            const bool vld = (i0 < CC);       // i0 even, so i0+1 <= 99 too
            float2 P[NB];
            #pragma unroll
            for (int jj = 0; jj < NB; ++jj)
                P[jj] = vld ? *reinterpret_cast<const float2*>(&M[(jb + jj) * CC + i0])
                            : make_float2(0.f, 0.f);
            for (int k = jend + w; k < CC; k += 4) {
                const int kr = k - jend;                 // wave-uniform (runtime)
                const int khалf = 0;                     // (unused placeholder)
                float bk[NB];
                #pragma unroll
                for (int jj = 0; jj < NB; ++jj) {
                    const float src = (kr & 1) ? P[jj].y : P[jj].x;
                    bk[jj] = lane_bcast_u(src, kr >> 1);
                }
                if (vld) {
                    float2 a = *reinterpret_cast<const float2*>(&M[k * CC + i0]);
                    #pragma unroll
                    for (int jj = 0; jj < NB; ++jj) {
                        a.x -= P[jj].x * bk[jj];
                        a.y -= P[jj].y * bk[jj];
                    }
                    *reinterpret_cast<float2*>(&M[k * CC + i0]) = a;
                }
            }
        }
        __syncthreads();
    }

    // pack frags (28 over 4 waves): lane l: d = dt*16+(l&15),
    // c = cs*32+(l>>4)*8+j.
    //   c<100:  L[d][c]*LOG2E (0 above diagonal / pad rows)
    //   c==100: bf16(u[d]*LOG2E), or -1e30 for pad rows d>=100
    //   c==101: residual u*LOG2E - u_hi (0 for pad rows)
    const int tx = l & 15;
    const int ty = l >> 4;
    unsigned short* outp = Lb + (size_t)b * (NDT * NCS * 64 * 8);
    for (int f = w; f < NDT * NCS; f += 4) {
        const int dt = f >> 2, cs = f & 3;
        const int d  = dt * 16 + tx;
        const int c0 = cs * 32 + ty * 8;
        unsigned short v[8];
        #pragma unroll
        for (int j = 0; j < 8; ++j) {
            const int c = c0 + j;
            float x = 0.0f;
            if (c < CC) {
                if (d < CC && c <= d) x = M[c * CC + d] * LOG2E;
            } else if (c == CC) {
                if (d < CC) x = bf2f(f2bf(u[(size_t)b * CC + d] * LOG2E));
                else        x = -1e30f;              // pad row kill switch
            } else if (c == CC + 1) {
                if (d < CC) {
                    const float t = u[(size_t)b * CC + d] * LOG2E;
                    x = t - bf2f(f2bf(t));           // residual
                }
            }
            v[j] = f2bf(x);
        }
        uint4 pk;
        pk.x = (unsigned)v[0] | ((unsigned)v[1] << 16);
        pk.y = (unsigned)v[2] | ((unsigned)v[3] << 16);
        pk.z = (unsigned)v[4] | ((unsigned)v[5] << 16);
        pk.w = (unsigned)v[6] | ((unsigned)v[7] << 16);
        reinterpret_cast<uint4*>(outp)[f * 64 + l] = pk;
    }
}

// ---------------- K2: MFMA matmul + base-2 softmax + mean ----------------
__global__ __launch_bounds__(256, 1)
void pred_kernel(const unsigned short* __restrict__ Lb,
                 const unsigned short* __restrict__ zb,
                 float* __restrict__ out) {
    __shared__ float red[4 * NDT * 16];
    const int tid = threadIdx.x, b = blockIdx.x;
    const int w  = tid >> 6;
    const int l  = tid & 63;
    const int li = l & 15;
    const int hi = l >> 4;

    // persistent L-frags: 28 x 4 VGPR = 112 VGPR
    s8 Bf[NDT][NCS];
    const s8* Lb8 = reinterpret_cast<const s8*>(Lb + (size_t)b * (NDT * NCS * 64 * 8));
    #pragma unroll
    for (int dt = 0; dt < NDT; ++dt)
        #pragma unroll
        for (int cs = 0; cs < NCS; ++cs)
            Bf[dt][cs] = Lb8[(dt * NCS + cs) * 64 + l];

    float meanAcc[NDT][4];
    #pragma unroll
    for (int dt = 0; dt < NDT; ++dt)
        #pragma unroll
        for (int r = 0; r < 4; ++r) meanAcc[dt][r] = 0.0f;

    const s8* zb8 = reinterpret_cast<const s8*>(zb);

    for (int st = w; st < NST; st += 4) {
        s8 Af[NCS];
        #pragma unroll
        for (int cs = 0; cs < NCS; ++cs)
            Af[cs] = zb8[(st * NCS + cs) * 64 + l];

        f4 acc[NDT];
        #pragma unroll
        for (int dt = 0; dt < NDT; ++dt) acc[dt] = (f4){0.f, 0.f, 0.f, 0.f};

        // swapped operands: D[row=d][col=s]; lane: d = dt*16+hi*4+r, s = st*16+li
        #pragma unroll
        for (int cs = 0; cs < NCS; ++cs)
            #pragma unroll
            for (int dt = 0; dt < NDT; ++dt)
                acc[dt] = __builtin_amdgcn_mfma_f32_16x16x32_bf16(
                              Bf[dt][cs], Af[cs], acc[dt], 0, 0, 0);

        // base-2 softmax over d (no max-subtract; |logit| small, fp32-safe).
        float rs01 = 0.0f, rs23 = 0.0f;
        #pragma unroll
        for (int dt = 0; dt < NDT; ++dt) {
            acc[dt][0] = __builtin_amdgcn_exp2f(acc[dt][0]);
            acc[dt][1] = __builtin_amdgcn_exp2f(acc[dt][1]);
            acc[dt][2] = __builtin_amdgcn_exp2f(acc[dt][2]);
            acc[dt][3] = __builtin_amdgcn_exp2f(acc[dt][3]);
            rs01 += acc[dt][0] + acc[dt][1];
            rs23 += acc[dt][2] + acc[dt][3];
        }
        float rs = rs01 + rs23;
        rs += __shfl_xor(rs, 16);
        rs += __shfl_xor(rs, 32);
        const float wgt = (st * 16 + li < SS) ? __builtin_amdgcn_rcpf(rs) : 0.0f;
        #pragma unroll
        for (int dt = 0; dt < NDT; ++dt)
            #pragma unroll
            for (int r = 0; r < 4; ++r) meanAcc[dt][r] += acc[dt][r] * wgt;
    }

    // reduce across the 16 li lanes (same d, different s)
    #pragma unroll
    for (int dt = 0; dt < NDT; ++dt)
        #pragma unroll
        for (int r = 0; r < 4; ++r) {
            float v = meanAcc[dt][r];
            v += __shfl_xor(v, 1);
            v += __shfl_xor(v, 2);
            v += __shfl_xor(v, 4);
            v += __shfl_xor(v, 8);
            if (li == 0) red[w * (NDT * 16) + dt * 16 + hi * 4 + r] = v;
        }
    __syncthreads();
    if (tid < CC) {
        const float sum = red[tid] + red[NDT * 16 + tid] +
                          red[2 * NDT * 16 + tid] + red[3 * NDT * 16 + tid];
        out[(size_t)b * CC + tid] = sum * (1.0f / (float)SS);
    }
}

extern "C" void kernel_launch(void* const* d_in, const int* in_sizes, int n_in,
                              void* d_out, int out_size, void* d_ws, size_t ws_size,
                              hipStream_t stream) {
    const float* u   = (const float*)d_in[0];
    const float* cov = (const float*)d_in[1];
    const float* z   = (const float*)d_in[2];
    float* outp = (float*)d_out;
    const int B = in_sizes[0] / CC;          // 1024

    unsigned short* zb = (unsigned short*)d_ws;                       // 258 KB
    unsigned short* Lbf = (unsigned short*)((char*)d_ws + (1 << 20)); // 29.4 MB

    zconv_kernel<<<dim3(NST), dim3(256), 0, stream>>>(z, zb);
    chol_kernel <<<dim3(B),   dim3(256), 0, stream>>>(cov, u, Lbf);
    pred_kernel <<<dim3(B),   dim3(256), 0, stream>>>(Lbf, zb, outp);
}

// Round 11
// 137.550 us; speedup vs baseline: 1.1573x; 1.1573x over previous
//
#include <hip/hip_runtime.h>

// GaussianSamplingPredict: B=1024, C=100, S=1000
//   L = cholesky(cov + 1e-6 I); t[b,s,d] = u[b,d] + sum_c z[s,c]*L[b,d,c]
//   out[b,d] = mean_s softmax_d(t[b,s,:])[d]
//
// R10: kill the chol scratch spill. R8/R9's 182 MB write overage = P[16]
// float2 trailing cache spilled once per panel (178 KB/block matches
// 32 regs x 64 lanes x 4 waves x 6 panels); launch_bounds(256,4) caps VGPR
// at 64 (cap = 256/arg) and the R8 live set no longer fit. Fix:
//  (a) launch_bounds(256,3) -> cap ~85, 3 blocks/CU x 4 waves = 12 waves/CU
//  (b) fuse bk broadcast into the FMA loop (bk live 16 -> 1), hoist
//      readfirstlane once per row. jj accumulation order unchanged ->
//      absmax must stay bit-identical 9.77e-4.

#define CC    100
#define SS    1000
#define EPSF  1e-6f
#define NB    16     // Cholesky panel width
#define NDT   7      // d-tiles: 7*16 = 112 >= 100
#define NCS   4      // c-steps: 4*32 = 128 >= 102
#define NST   63     // s-tiles: 63*16 = 1008 >= 1000
#define LOG2E 1.44269504088896340736f

typedef short  s8 __attribute__((ext_vector_type(8)));   // 8 bf16 (4 VGPR)
typedef float  f4 __attribute__((ext_vector_type(4)));

__device__ inline unsigned short f2bf(float x) {          // round-nearest-even
    unsigned u = __float_as_uint(x);
    return (unsigned short)((u + 0x7fffu + ((u >> 16) & 1u)) >> 16);
}
__device__ inline float bf2f(unsigned short h) {
    return __uint_as_float(((unsigned)h) << 16);
}
__device__ inline float lane_bcast(float x, int lane) {   // provably-uniform idx
    return __int_as_float(__builtin_amdgcn_readlane(__float_as_int(x), lane));
}

// ---------------- K0: pack z -> bf16 frags (+ ones at c=100,101) ----------------
// frag layout: [stile][cstep][lane][j]; lane l: s = stile*16+(l&15),
// c = cstep*32 + (l>>4)*8 + j.
__global__ __launch_bounds__(256)
void zconv_kernel(const float* __restrict__ z, unsigned short* __restrict__ zb) {
    const int stile = blockIdx.x;            // 0..62
    const int cs = threadIdx.x >> 6;
    const int l  = threadIdx.x & 63;
    const int s  = stile * 16 + (l & 15);
    const int c0 = cs * 32 + (l >> 4) * 8;
    unsigned short v[8];
    #pragma unroll
    for (int j = 0; j < 8; ++j) {
        const int c = c0 + j;
        float x = 0.0f;
        if (c < CC)      x = (s < SS) ? z[(size_t)s * CC + c] : 0.0f;
        else if (c <= CC + 1) x = 1.0f;          // u_hi / u_lo slots
        v[j] = f2bf(x);
    }
    uint4 pk;
    pk.x = (unsigned)v[0] | ((unsigned)v[1] << 16);
    pk.y = (unsigned)v[2] | ((unsigned)v[3] << 16);
    pk.z = (unsigned)v[4] | ((unsigned)v[5] << 16);
    pk.w = (unsigned)v[6] | ((unsigned)v[7] << 16);
    reinterpret_cast<uint4*>(zb)[(stile * NCS + cs) * 64 + l] = pk;
}

// Register-resident panel factorization (wave 0 only).
// Lane l holds columns 2l, 2l+1 of each panel row (float2, b64 LDS traffic).
template<int NPAN>
__device__ inline void panel_factor(float* __restrict__ M, int jb, int l) {
    float2 P[NPAN];
    const int c0 = 2 * l;
    const bool vld = (c0 < CC);
    #pragma unroll
    for (int jj = 0; jj < NPAN; ++jj)
        P[jj] = vld ? *reinterpret_cast<const float2*>(&M[(jb + jj) * CC + c0])
                    : make_float2(0.f, 0.f);
    #pragma unroll
    for (int jj = 0; jj < NPAN; ++jj) {
        const int j = jb + jj;                 // provably uniform
        const float dsrc  = (j & 1) ? P[jj].y : P[jj].x;
        const float val   = lane_bcast(dsrc, j >> 1);
        const float dinv  = rsqrtf(val);
        const float s     = val * dinv;
        const float dinv2 = dinv * dinv;
        #pragma unroll
        for (int kk = jj + 1; kk < NPAN; ++kk) {
            const int k = jb + kk;
            const float tsrc = (k & 1) ? P[jj].y : P[jj].x;
            const float t = lane_bcast(tsrc, k >> 1) * dinv2;
            P[kk].x -= P[jj].x * t;
            P[kk].y -= P[jj].y * t;
        }
        P[jj].x = (c0 == j)     ? s : ((c0 > j)     ? P[jj].x * dinv : P[jj].x);
        P[jj].y = (c0 + 1 == j) ? s : ((c0 + 1 > j) ? P[jj].y * dinv : P[jj].y);
    }
    #pragma unroll
    for (int jj = 0; jj < NPAN; ++jj)
        if (vld) *reinterpret_cast<float2*>(&M[(jb + jj) * CC + c0]) = P[jj];
}

// ---------------- K1: blocked Cholesky (4 waves) + frag pack ----------------
// Storage: M[x*100+y] = L[y][x] for y>=x. Pack applies LOG2E scaling and
// appends u_hi/u_lo columns (c=100/101) and -1e30 pad sentinels.
__global__ __launch_bounds__(256, 3)
void chol_kernel(const float* __restrict__ cov, const float* __restrict__ u,
                 unsigned short* __restrict__ Lb) {
    __shared__ float M[CC * CC];
    const int tid = threadIdx.x;
    const int w   = tid >> 6;
    const int l   = tid & 63;
    const int b   = blockIdx.x;

    const float4* c4 = reinterpret_cast<const float4*>(cov + (size_t)b * CC * CC);
    for (int t = tid; t < CC * CC / 4; t += 256)
        reinterpret_cast<float4*>(M)[t] = c4[t];
    __syncthreads();
    for (int d = tid; d < CC; d += 256) M[d * CC + d] += EPSF;
    __syncthreads();

    for (int jb = 0; jb < CC; jb += NB) {
        const int jend = (jb + NB < CC) ? jb + NB : CC;

        // ---- panel factorization in wave-0 registers ----
        if (w == 0) {
            if (jend - jb == NB) panel_factor<NB>(M, jb, l);
            else                 panel_factor<CC - (CC / NB) * NB>(M, jb, l); // 4
        }
        __syncthreads();

        // ---- rank-16 trailing update, rows split across 4 waves ----
        // Lane l owns trailing columns i0 = jend+2l, i0+1 (float2).
        // Panel column k broadcast from the owning lane's P-cache via
        // v_readlane (index readfirstlane'd once per row: w-derived indices
        // are runtime-uniform but divergent to the compiler). bk fused into
        // the FMA loop: live set 1, not 16 (R8/R9 spilled at the 64-reg cap).
        if (jend < CC) {
            const int i0 = jend + 2 * l;
            const bool vld = (i0 < CC);       // i0 even, so i0+1 <= 99 too
            float2 P[NB];
            #pragma unroll
            for (int jj = 0; jj < NB; ++jj)
                P[jj] = vld ? *reinterpret_cast<const float2*>(&M[(jb + jj) * CC + i0])
                            : make_float2(0.f, 0.f);
            for (int k = jend + w; k < CC; k += 4) {
                const int kr = k - jend;                 // wave-uniform (runtime)
                const int sl = __builtin_amdgcn_readfirstlane(kr >> 1);
                const bool odd = (kr & 1) != 0;
                if (vld) {
                    float2 a = *reinterpret_cast<const float2*>(&M[k * CC + i0]);
                    #pragma unroll
                    for (int jj = 0; jj < NB; ++jj) {
                        const float src = odd ? P[jj].y : P[jj].x;
                        const float bk = lane_bcast(src, sl);
                        a.x -= P[jj].x * bk;
                        a.y -= P[jj].y * bk;
                    }
                    *reinterpret_cast<float2*>(&M[k * CC + i0]) = a;
                }
            }
        }
        __syncthreads();
    }

    // pack frags (28 over 4 waves): lane l: d = dt*16+(l&15),
    // c = cs*32+(l>>4)*8+j.
    //   c<100:  L[d][c]*LOG2E (0 above diagonal / pad rows)
    //   c==100: bf16(u[d]*LOG2E), or -1e30 for pad rows d>=100
    //   c==101: residual u*LOG2E - u_hi (0 for pad rows)
    const int tx = l & 15;
    const int ty = l >> 4;
    unsigned short* outp = Lb + (size_t)b * (NDT * NCS * 64 * 8);
    for (int f = w; f < NDT * NCS; f += 4) {
        const int dt = f >> 2, cs = f & 3;
        const int d  = dt * 16 + tx;
        const int c0 = cs * 32 + ty * 8;
        unsigned short v[8];
        #pragma unroll
        for (int j = 0; j < 8; ++j) {
            const int c = c0 + j;
            float x = 0.0f;
            if (c < CC) {
                if (d < CC && c <= d) x = M[c * CC + d] * LOG2E;
            } else if (c == CC) {
                if (d < CC) x = bf2f(f2bf(u[(size_t)b * CC + d] * LOG2E));
                else        x = -1e30f;              // pad row kill switch
            } else if (c == CC + 1) {
                if (d < CC) {
                    const float t = u[(size_t)b * CC + d] * LOG2E;
                    x = t - bf2f(f2bf(t));           // residual
                }
            }
            v[j] = f2bf(x);
        }
        uint4 pk;
        pk.x = (unsigned)v[0] | ((unsigned)v[1] << 16);
        pk.y = (unsigned)v[2] | ((unsigned)v[3] << 16);
        pk.z = (unsigned)v[4] | ((unsigned)v[5] << 16);
        pk.w = (unsigned)v[6] | ((unsigned)v[7] << 16);
        reinterpret_cast<uint4*>(outp)[f * 64 + l] = pk;
    }
}

// ---------------- K2: MFMA matmul + base-2 softmax + mean ----------------
__global__ __launch_bounds__(256, 1)
void pred_kernel(const unsigned short* __restrict__ Lb,
                 const unsigned short* __restrict__ zb,
                 float* __restrict__ out) {
    __shared__ float red[4 * NDT * 16];
    const int tid = threadIdx.x, b = blockIdx.x;
    const int w  = tid >> 6;
    const int l  = tid & 63;
    const int li = l & 15;
    const int hi = l >> 4;

    // persistent L-frags: 28 x 4 VGPR = 112 VGPR
    s8 Bf[NDT][NCS];
    const s8* Lb8 = reinterpret_cast<const s8*>(Lb + (size_t)b * (NDT * NCS * 64 * 8));
    #pragma unroll
    for (int dt = 0; dt < NDT; ++dt)
        #pragma unroll
        for (int cs = 0; cs < NCS; ++cs)
            Bf[dt][cs] = Lb8[(dt * NCS + cs) * 64 + l];

    float meanAcc[NDT][4];
    #pragma unroll
    for (int dt = 0; dt < NDT; ++dt)
        #pragma unroll
        for (int r = 0; r < 4; ++r) meanAcc[dt][r] = 0.0f;

    const s8* zb8 = reinterpret_cast<const s8*>(zb);

    for (int st = w; st < NST; st += 4) {
        s8 Af[NCS];
        #pragma unroll
        for (int cs = 0; cs < NCS; ++cs)
            Af[cs] = zb8[(st * NCS + cs) * 64 + l];

        f4 acc[NDT];
        #pragma unroll
        for (int dt = 0; dt < NDT; ++dt) acc[dt] = (f4){0.f, 0.f, 0.f, 0.f};

        // swapped operands: D[row=d][col=s]; lane: d = dt*16+hi*4+r, s = st*16+li
        #pragma unroll
        for (int cs = 0; cs < NCS; ++cs)
            #pragma unroll
            for (int dt = 0; dt < NDT; ++dt)
                acc[dt] = __builtin_amdgcn_mfma_f32_16x16x32_bf16(
                              Bf[dt][cs], Af[cs], acc[dt], 0, 0, 0);

        // base-2 softmax over d (no max-subtract; |logit| small, fp32-safe).
        float rs01 = 0.0f, rs23 = 0.0f;
        #pragma unroll
        for (int dt = 0; dt < NDT; ++dt) {
            acc[dt][0] = __builtin_amdgcn_exp2f(acc[dt][0]);
            acc[dt][1] = __builtin_amdgcn_exp2f(acc[dt][1]);
            acc[dt][2] = __builtin_amdgcn_exp2f(acc[dt][2]);
            acc[dt][3] = __builtin_amdgcn_exp2f(acc[dt][3]);
            rs01 += acc[dt][0] + acc[dt][1];
            rs23 += acc[dt][2] + acc[dt][3];
        }
        float rs = rs01 + rs23;
        rs += __shfl_xor(rs, 16);
        rs += __shfl_xor(rs, 32);
        const float wgt = (st * 16 + li < SS) ? __builtin_amdgcn_rcpf(rs) : 0.0f;
        #pragma unroll
        for (int dt = 0; dt < NDT; ++dt)
            #pragma unroll
            for (int r = 0; r < 4; ++r) meanAcc[dt][r] += acc[dt][r] * wgt;
    }

    // reduce across the 16 li lanes (same d, different s)
    #pragma unroll
    for (int dt = 0; dt < NDT; ++dt)
        #pragma unroll
        for (int r = 0; r < 4; ++r) {
            float v = meanAcc[dt][r];
            v += __shfl_xor(v, 1);
            v += __shfl_xor(v, 2);
            v += __shfl_xor(v, 4);
            v += __shfl_xor(v, 8);
            if (li == 0) red[w * (NDT * 16) + dt * 16 + hi * 4 + r] = v;
        }
    __syncthreads();
    if (tid < CC) {
        const float sum = red[tid] + red[NDT * 16 + tid] +
                          red[2 * NDT * 16 + tid] + red[3 * NDT * 16 + tid];
        out[(size_t)b * CC + tid] = sum * (1.0f / (float)SS);
    }
}

extern "C" void kernel_launch(void* const* d_in, const int* in_sizes, int n_in,
                              void* d_out, int out_size, void* d_ws, size_t ws_size,
                              hipStream_t stream) {
    const float* u   = (const float*)d_in[0];
    const float* cov = (const float*)d_in[1];
    const float* z   = (const float*)d_in[2];
    float* outp = (float*)d_out;
    const int B = in_sizes[0] / CC;          // 1024

    unsigned short* zb = (unsigned short*)d_ws;                       // 258 KB
    unsigned short* Lbf = (unsigned short*)((char*)d_ws + (1 << 20)); // 29.4 MB

    zconv_kernel<<<dim3(NST), dim3(256), 0, stream>>>(z, zb);
    chol_kernel <<<dim3(B),   dim3(256), 0, stream>>>(cov, u, Lbf);
    pred_kernel <<<dim3(B),   dim3(256), 0, stream>>>(Lbf, zb, outp);
}

// Round 12
// 132.387 us; speedup vs baseline: 1.2024x; 1.0390x over previous
//
#include <hip/hip_runtime.h>

// GaussianSamplingPredict: B=1024, C=100, S=1000
//   L = cholesky(cov + 1e-6 I); t[b,s,d] = u[b,d] + sum_c z[s,c]*L[b,d,c]
//   out[b,d] = mean_s softmax_d(t[b,s,:])[d]
//
// R11: trailing-update bk via transposed panel buffer Pt.
//  - R7's bk = 16 scalar ds_read_b32/row -> 4.2k DS instrs/matrix (~41 us at
//    the ~5.8cyc/instr DS rate) = the chol bottleneck.
//  - R8/R10's readlane fix traded DS for VALU->SGPR hazards + spill: worse.
//  - Now: wave 0 writes the finalized panel FROM REGISTERS into Pt[kr][jj]
//    (8 ds_write_b128/panel). Trailing reads bk as 4 uniform-address
//    ds_read_b128 (broadcast, conflict-free, VGPR dest -> no hazard).
//    Trailing DS/row: 20 -> 6. FMA order unchanged -> absmax bit-identical.

#define CC    100
#define SS    1000
#define EPSF  1e-6f
#define NB    16     // Cholesky panel width
#define NDT   7      // d-tiles: 7*16 = 112 >= 100
#define NCS   4      // c-steps: 4*32 = 128 >= 102
#define NST   63     // s-tiles: 63*16 = 1008 >= 1000
#define LOG2E 1.44269504088896340736f
#define PTROWS 84    // max trailing rows: CC - 16

typedef short  s8 __attribute__((ext_vector_type(8)));   // 8 bf16 (4 VGPR)
typedef float  f4 __attribute__((ext_vector_type(4)));

__device__ inline unsigned short f2bf(float x) {          // round-nearest-even
    unsigned u = __float_as_uint(x);
    return (unsigned short)((u + 0x7fffu + ((u >> 16) & 1u)) >> 16);
}
__device__ inline float bf2f(unsigned short h) {
    return __uint_as_float(((unsigned)h) << 16);
}
__device__ inline float lane_bcast(float x, int lane) {   // provably-uniform idx
    return __int_as_float(__builtin_amdgcn_readlane(__float_as_int(x), lane));
}

// ---------------- K0: pack z -> bf16 frags (+ ones at c=100,101) ----------------
// frag layout: [stile][cstep][lane][j]; lane l: s = stile*16+(l&15),
// c = cstep*32 + (l>>4)*8 + j.
__global__ __launch_bounds__(256)
void zconv_kernel(const float* __restrict__ z, unsigned short* __restrict__ zb) {
    const int stile = blockIdx.x;            // 0..62
    const int cs = threadIdx.x >> 6;
    const int l  = threadIdx.x & 63;
    const int s  = stile * 16 + (l & 15);
    const int c0 = cs * 32 + (l >> 4) * 8;
    unsigned short v[8];
    #pragma unroll
    for (int j = 0; j < 8; ++j) {
        const int c = c0 + j;
        float x = 0.0f;
        if (c < CC)      x = (s < SS) ? z[(size_t)s * CC + c] : 0.0f;
        else if (c <= CC + 1) x = 1.0f;          // u_hi / u_lo slots
        v[j] = f2bf(x);
    }
    uint4 pk;
    pk.x = (unsigned)v[0] | ((unsigned)v[1] << 16);
    pk.y = (unsigned)v[2] | ((unsigned)v[3] << 16);
    pk.z = (unsigned)v[4] | ((unsigned)v[5] << 16);
    pk.w = (unsigned)v[6] | ((unsigned)v[7] << 16);
    reinterpret_cast<uint4*>(zb)[(stile * NCS + cs) * 64 + l] = pk;
}

// Register-resident panel factorization (wave 0 only).
// Lane l holds columns 2l, 2l+1 of each panel row (float2, b64 LDS traffic).
// On full panels also writes the transposed panel buffer Pt[kr][jj]
// (kr = column - jend) straight from registers for the trailing update.
template<int NPAN>
__device__ inline void panel_factor(float* __restrict__ M, float* __restrict__ Pt,
                                    int jb, int jend, int l) {
    float2 P[NPAN];
    const int c0 = 2 * l;
    const bool vld = (c0 < CC);
    #pragma unroll
    for (int jj = 0; jj < NPAN; ++jj)
        P[jj] = vld ? *reinterpret_cast<const float2*>(&M[(jb + jj) * CC + c0])
                    : make_float2(0.f, 0.f);
    #pragma unroll
    for (int jj = 0; jj < NPAN; ++jj) {
        const int j = jb + jj;                 // provably uniform
        const float dsrc  = (j & 1) ? P[jj].y : P[jj].x;
        const float val   = lane_bcast(dsrc, j >> 1);
        const float dinv  = rsqrtf(val);
        const float s     = val * dinv;
        const float dinv2 = dinv * dinv;
        #pragma unroll
        for (int kk = jj + 1; kk < NPAN; ++kk) {
            const int k = jb + kk;
            const float tsrc = (k & 1) ? P[jj].y : P[jj].x;
            const float t = lane_bcast(tsrc, k >> 1) * dinv2;
            P[kk].x -= P[jj].x * t;
            P[kk].y -= P[jj].y * t;
        }
        P[jj].x = (c0 == j)     ? s : ((c0 > j)     ? P[jj].x * dinv : P[jj].x);
        P[jj].y = (c0 + 1 == j) ? s : ((c0 + 1 > j) ? P[jj].y * dinv : P[jj].y);
    }
    #pragma unroll
    for (int jj = 0; jj < NPAN; ++jj)
        if (vld) *reinterpret_cast<float2*>(&M[(jb + jj) * CC + c0]) = P[jj];

    // transposed panel write (full panels only): lane l owns columns 2l,2l+1
    // -> Pt rows kr0 = 2l - jend and kr0+1, each NPAN contiguous floats.
    if (NPAN == NB && jend < CC) {
        const int kr0 = c0 - jend;
        if (kr0 >= 0 && c0 < CC) {
            #pragma unroll
            for (int ch = 0; ch < NPAN / 4; ++ch) {
                float4 vx, vy;
                vx.x = P[ch*4+0].x; vx.y = P[ch*4+1].x;
                vx.z = P[ch*4+2].x; vx.w = P[ch*4+3].x;
                vy.x = P[ch*4+0].y; vy.y = P[ch*4+1].y;
                vy.z = P[ch*4+2].y; vy.w = P[ch*4+3].y;
                *reinterpret_cast<float4*>(&Pt[kr0 * NB + ch * 4]) = vx;
                *reinterpret_cast<float4*>(&Pt[(kr0 + 1) * NB + ch * 4]) = vy;
            }
        }
    }
}

// ---------------- K1: blocked Cholesky (4 waves) + frag pack ----------------
// Storage: M[x*100+y] = L[y][x] for y>=x. Pack applies LOG2E scaling and
// appends u_hi/u_lo columns (c=100/101) and -1e30 pad sentinels.
__global__ __launch_bounds__(256, 3)
void chol_kernel(const float* __restrict__ cov, const float* __restrict__ u,
                 unsigned short* __restrict__ Lb) {
    __shared__ alignas(16) float M[CC * CC];
    __shared__ alignas(16) float Pt[PTROWS * NB];   // 5.4 KB
    const int tid = threadIdx.x;
    const int w   = tid >> 6;
    const int l   = tid & 63;
    const int b   = blockIdx.x;

    const float4* c4 = reinterpret_cast<const float4*>(cov + (size_t)b * CC * CC);
    for (int t = tid; t < CC * CC / 4; t += 256)
        reinterpret_cast<float4*>(M)[t] = c4[t];
    __syncthreads();
    for (int d = tid; d < CC; d += 256) M[d * CC + d] += EPSF;
    __syncthreads();

    for (int jb = 0; jb < CC; jb += NB) {
        const int jend = (jb + NB < CC) ? jb + NB : CC;

        // ---- panel factorization in wave-0 registers (+ Pt write) ----
        if (w == 0) {
            if (jend - jb == NB) panel_factor<NB>(M, Pt, jb, jend, l);
            else                 panel_factor<CC - (CC / NB) * NB>(M, Pt, jb, jend, l);
        }
        __syncthreads();

        // ---- rank-16 trailing update, rows split across 4 waves ----
        // Lane l owns trailing columns i0 = jend+2l, i0+1 (float2).
        // bk for row k = Pt[k-jend][0..15]: 4 uniform-address ds_read_b128
        // (hardware broadcast; VGPR dest -> no SGPR hazard, no waterfall).
        if (jend < CC) {
            const int i0 = jend + 2 * l;
            const bool vld = (i0 < CC);       // i0 even, so i0+1 <= 99 too
            float2 P[NB];
            #pragma unroll
            for (int jj = 0; jj < NB; ++jj)
                P[jj] = vld ? *reinterpret_cast<const float2*>(&M[(jb + jj) * CC + i0])
                            : make_float2(0.f, 0.f);
            for (int k = jend + w; k < CC; k += 4) {
                const int kr = k - jend;
                if (vld) {
                    const float4* PtR = reinterpret_cast<const float4*>(&Pt[kr * NB]);
                    const float4 b0 = PtR[0], b1 = PtR[1], b2 = PtR[2], b3 = PtR[3];
                    const float bk[NB] = {b0.x, b0.y, b0.z, b0.w,
                                          b1.x, b1.y, b1.z, b1.w,
                                          b2.x, b2.y, b2.z, b2.w,
                                          b3.x, b3.y, b3.z, b3.w};
                    float2 a = *reinterpret_cast<const float2*>(&M[k * CC + i0]);
                    #pragma unroll
                    for (int jj = 0; jj < NB; ++jj) {
                        a.x -= P[jj].x * bk[jj];
                        a.y -= P[jj].y * bk[jj];
                    }
                    *reinterpret_cast<float2*>(&M[k * CC + i0]) = a;
                }
            }
        }
        __syncthreads();
    }

    // pack frags (28 over 4 waves): lane l: d = dt*16+(l&15),
    // c = cs*32+(l>>4)*8+j.
    //   c<100:  L[d][c]*LOG2E (0 above diagonal / pad rows)
    //   c==100: bf16(u[d]*LOG2E), or -1e30 for pad rows d>=100
    //   c==101: residual u*LOG2E - u_hi (0 for pad rows)
    const int tx = l & 15;
    const int ty = l >> 4;
    unsigned short* outp = Lb + (size_t)b * (NDT * NCS * 64 * 8);
    for (int f = w; f < NDT * NCS; f += 4) {
        const int dt = f >> 2, cs = f & 3;
        const int d  = dt * 16 + tx;
        const int c0 = cs * 32 + ty * 8;
        unsigned short v[8];
        #pragma unroll
        for (int j = 0; j < 8; ++j) {
            const int c = c0 + j;
            float x = 0.0f;
            if (c < CC) {
                if (d < CC && c <= d) x = M[c * CC + d] * LOG2E;
            } else if (c == CC) {
                if (d < CC) x = bf2f(f2bf(u[(size_t)b * CC + d] * LOG2E));
                else        x = -1e30f;              // pad row kill switch
            } else if (c == CC + 1) {
                if (d < CC) {
                    const float t = u[(size_t)b * CC + d] * LOG2E;
                    x = t - bf2f(f2bf(t));           // residual
                }
            }
            v[j] = f2bf(x);
        }
        uint4 pk;
        pk.x = (unsigned)v[0] | ((unsigned)v[1] << 16);
        pk.y = (unsigned)v[2] | ((unsigned)v[3] << 16);
        pk.z = (unsigned)v[4] | ((unsigned)v[5] << 16);
        pk.w = (unsigned)v[6] | ((unsigned)v[7] << 16);
        reinterpret_cast<uint4*>(outp)[f * 64 + l] = pk;
    }
}

// ---------------- K2: MFMA matmul + base-2 softmax + mean ----------------
__global__ __launch_bounds__(256, 1)
void pred_kernel(const unsigned short* __restrict__ Lb,
                 const unsigned short* __restrict__ zb,
                 float* __restrict__ out) {
    __shared__ float red[4 * NDT * 16];
    const int tid = threadIdx.x, b = blockIdx.x;
    const int w  = tid >> 6;
    const int l  = tid & 63;
    const int li = l & 15;
    const int hi = l >> 4;

    // persistent L-frags: 28 x 4 VGPR = 112 VGPR
    s8 Bf[NDT][NCS];
    const s8* Lb8 = reinterpret_cast<const s8*>(Lb + (size_t)b * (NDT * NCS * 64 * 8));
    #pragma unroll
    for (int dt = 0; dt < NDT; ++dt)
        #pragma unroll
        for (int cs = 0; cs < NCS; ++cs)
            Bf[dt][cs] = Lb8[(dt * NCS + cs) * 64 + l];

    float meanAcc[NDT][4];
    #pragma unroll
    for (int dt = 0; dt < NDT; ++dt)
        #pragma unroll
        for (int r = 0; r < 4; ++r) meanAcc[dt][r] = 0.0f;

    const s8* zb8 = reinterpret_cast<const s8*>(zb);

    for (int st = w; st < NST; st += 4) {
        s8 Af[NCS];
        #pragma unroll
        for (int cs = 0; cs < NCS; ++cs)
            Af[cs] = zb8[(st * NCS + cs) * 64 + l];

        f4 acc[NDT];
        #pragma unroll
        for (int dt = 0; dt < NDT; ++dt) acc[dt] = (f4){0.f, 0.f, 0.f, 0.f};

        // swapped operands: D[row=d][col=s]; lane: d = dt*16+hi*4+r, s = st*16+li
        #pragma unroll
        for (int cs = 0; cs < NCS; ++cs)
            #pragma unroll
            for (int dt = 0; dt < NDT; ++dt)
                acc[dt] = __builtin_amdgcn_mfma_f32_16x16x32_bf16(
                              Bf[dt][cs], Af[cs], acc[dt], 0, 0, 0);

        // base-2 softmax over d (no max-subtract; |logit| small, fp32-safe).
        float rs01 = 0.0f, rs23 = 0.0f;
        #pragma unroll
        for (int dt = 0; dt < NDT; ++dt) {
            acc[dt][0] = __builtin_amdgcn_exp2f(acc[dt][0]);
            acc[dt][1] = __builtin_amdgcn_exp2f(acc[dt][1]);
            acc[dt][2] = __builtin_amdgcn_exp2f(acc[dt][2]);
            acc[dt][3] = __builtin_amdgcn_exp2f(acc[dt][3]);
            rs01 += acc[dt][0] + acc[dt][1];
            rs23 += acc[dt][2] + acc[dt][3];
        }
        float rs = rs01 + rs23;
        rs += __shfl_xor(rs, 16);
        rs += __shfl_xor(rs, 32);
        const float wgt = (st * 16 + li < SS) ? __builtin_amdgcn_rcpf(rs) : 0.0f;
        #pragma unroll
        for (int dt = 0; dt < NDT; ++dt)
            #pragma unroll
            for (int r = 0; r < 4; ++r) meanAcc[dt][r] += acc[dt][r] * wgt;
    }

    // reduce across the 16 li lanes (same d, different s)
    #pragma unroll
    for (int dt = 0; dt < NDT; ++dt)
        #pragma unroll
        for (int r = 0; r < 4; ++r) {
            float v = meanAcc[dt][r];
            v += __shfl_xor(v, 1);
            v += __shfl_xor(v, 2);
            v += __shfl_xor(v, 4);
            v += __shfl_xor(v, 8);
            if (li == 0) red[w * (NDT * 16) + dt * 16 + hi * 4 + r] = v;
        }
    __syncthreads();
    if (tid < CC) {
        const float sum = red[tid] + red[NDT * 16 + tid] +
                          red[2 * NDT * 16 + tid] + red[3 * NDT * 16 + tid];
        out[(size_t)b * CC + tid] = sum * (1.0f / (float)SS);
    }
}

extern "C" void kernel_launch(void* const* d_in, const int* in_sizes, int n_in,
                              void* d_out, int out_size, void* d_ws, size_t ws_size,
                              hipStream_t stream) {
    const float* u   = (const float*)d_in[0];
    const float* cov = (const float*)d_in[1];
    const float* z   = (const float*)d_in[2];
    float* outp = (float*)d_out;
    const int B = in_sizes[0] / CC;          // 1024

    unsigned short* zb = (unsigned short*)d_ws;                       // 258 KB
    unsigned short* Lbf = (unsigned short*)((char*)d_ws + (1 << 20)); // 29.4 MB

    zconv_kernel<<<dim3(NST), dim3(256), 0, stream>>>(z, zb);
    chol_kernel <<<dim3(B),   dim3(256), 0, stream>>>(cov, u, Lbf);
    pred_kernel <<<dim3(B),   dim3(256), 0, stream>>>(Lbf, zb, outp);
}